// Round 7
// baseline (60.450 us; speedup 1.0000x reference)
//
#include <hip/hip_runtime.h>
#include <math.h>

#define N1 8192
#define N2 4096
#define N3 2048

typedef float f4 __attribute__((ext_vector_type(4)));

__device__ __forceinline__ float dot4(f4 u, f4 x, float acc) {
    return fmaf(u.x, x.x, fmaf(u.y, x.y, fmaf(u.z, x.z, fmaf(u.w, x.w, acc))));
}

// ---------- Kernel A: single saturated stream of ALL weight bytes ----------
// blocks [0,1024):    4 rows of w12 @ l1(recomputed in LDS)  -> a[4096] (raw dot; NT loads)
// blocks [1024,1280): 16 rows of w32 @ l3_state              -> b[4096] (NT loads)
// blocks [1280,1536): 8 rows of w23 @ l2_state               -> A[2048] (PLAIN loads:
//                     leaves w23 L3-resident for kB; these are the last-dispatched blocks)
// blocks 0..31 also publish l1 to d_out.
__global__ __launch_bounds__(256) void kA(const float* __restrict__ smi,
                                          const float* __restrict__ l1s,
                                          const float* __restrict__ w12,
                                          const float* __restrict__ w32,
                                          const float* __restrict__ w23,
                                          const float* __restrict__ l3s,
                                          const float* __restrict__ l2s,
                                          float* __restrict__ a_out,
                                          float* __restrict__ b_out,
                                          float* __restrict__ A_out,
                                          float* __restrict__ l1_out) {
    __shared__ float lds[N1];  // 32 KB (role 0 only uses it; 5 blocks/CU cap is fine)
    const int blk = blockIdx.x;
    const int t = threadIdx.x;

    if (blk < 1024) {
        // ---- role 0: 4 rows of w12 ----
        __shared__ float ws[4][4];
        const int r0 = blk * 4;
        {
            const f4* __restrict__ s4 = reinterpret_cast<const f4*>(smi);
            const f4* __restrict__ p4 = reinterpret_cast<const f4*>(l1s);
            f4* __restrict__ d4 = reinterpret_cast<f4*>(lds);
#pragma unroll
            for (int k = 0; k < 8; ++k) {
                const int i = t + k * 256;
                f4 s = s4[i];
                f4 p = p4[i];
                f4 r;
                r.x = fmaf(0.95f, p.x, 0.05f * tanhf(s.x));
                r.y = fmaf(0.95f, p.y, 0.05f * tanhf(s.y));
                r.z = fmaf(0.95f, p.z, 0.05f * tanhf(s.z));
                r.w = fmaf(0.95f, p.w, 0.05f * tanhf(s.w));
                d4[i] = r;
            }
        }
        __syncthreads();
        if (blk < 32) {
            const int i = blk * 256 + t;
            l1_out[i] = lds[i];
        }
        const f4* __restrict__ w0 = reinterpret_cast<const f4*>(w12) + (size_t)r0 * (N1 / 4);
        const f4* __restrict__ w1 = w0 + (N1 / 4);
        const f4* __restrict__ w2 = w1 + (N1 / 4);
        const f4* __restrict__ w3 = w2 + (N1 / 4);
        const f4* __restrict__ x1 = reinterpret_cast<const f4*>(lds);
        float a0 = 0.f, a1 = 0.f, a2 = 0.f, a3 = 0.f;
#pragma unroll
        for (int k = 0; k < 8; ++k) {
            const int i = t + k * 256;
            f4 xv = x1[i];
            a0 = dot4(__builtin_nontemporal_load(&w0[i]), xv, a0);
            a1 = dot4(__builtin_nontemporal_load(&w1[i]), xv, a1);
            a2 = dot4(__builtin_nontemporal_load(&w2[i]), xv, a2);
            a3 = dot4(__builtin_nontemporal_load(&w3[i]), xv, a3);
        }
#pragma unroll
        for (int off = 32; off; off >>= 1) {
            a0 += __shfl_down(a0, off, 64);
            a1 += __shfl_down(a1, off, 64);
            a2 += __shfl_down(a2, off, 64);
            a3 += __shfl_down(a3, off, 64);
        }
        if ((t & 63) == 0) {
            const int w = t >> 6;
            ws[w][0] = a0; ws[w][1] = a1; ws[w][2] = a2; ws[w][3] = a3;
        }
        __syncthreads();
        if (t < 4) a_out[r0 + t] = ws[0][t] + ws[1][t] + ws[2][t] + ws[3][t];
    } else if (blk < 1280) {
        // ---- role 1: 16 rows of w32 @ l3s ----
        __shared__ float ws[4][16];
        const int r0 = (blk - 1024) * 16;
        const f4* __restrict__ base = reinterpret_cast<const f4*>(w32) + (size_t)r0 * (N3 / 4);
        const f4* __restrict__ x3 = reinterpret_cast<const f4*>(l3s);
        f4 x0 = x3[t];
        f4 x1v = x3[t + 256];
        float acc[16];
#pragma unroll
        for (int rr = 0; rr < 16; ++rr) {
            f4 u0 = __builtin_nontemporal_load(&base[(size_t)rr * (N3 / 4) + t]);
            f4 u1 = __builtin_nontemporal_load(&base[(size_t)rr * (N3 / 4) + 256 + t]);
            acc[rr] = dot4(u1, x1v, dot4(u0, x0, 0.f));
        }
#pragma unroll
        for (int rr = 0; rr < 16; ++rr) {
            float v = acc[rr];
#pragma unroll
            for (int off = 32; off; off >>= 1) v += __shfl_down(v, off, 64);
            acc[rr] = v;
        }
        if ((t & 63) == 0) {
            const int w = t >> 6;
#pragma unroll
            for (int rr = 0; rr < 16; ++rr) ws[w][rr] = acc[rr];
        }
        __syncthreads();
        if (t < 16) b_out[r0 + t] = ws[0][t] + ws[1][t] + ws[2][t] + ws[3][t];
    } else {
        // ---- role 2: 8 rows of w23 @ l2s -> A (PLAIN loads: L3 prefetch for kB) ----
        __shared__ float ws[4][8];
        const int r0 = (blk - 1280) * 8;
        const f4* __restrict__ base = reinterpret_cast<const f4*>(w23) + (size_t)r0 * (N2 / 4);
        const f4* __restrict__ xs = reinterpret_cast<const f4*>(l2s);
        f4 xv[4];
#pragma unroll
        for (int k = 0; k < 4; ++k) xv[k] = xs[t + k * 256];
        float acc[8];
#pragma unroll
        for (int rr = 0; rr < 8; ++rr) {
            float v = 0.f;
#pragma unroll
            for (int k = 0; k < 4; ++k)
                v = dot4(base[(size_t)rr * (N2 / 4) + k * 256 + t], xv[k], v);
            acc[rr] = v;
        }
#pragma unroll
        for (int rr = 0; rr < 8; ++rr) {
            float v = acc[rr];
#pragma unroll
            for (int off = 32; off; off >>= 1) v += __shfl_down(v, off, 64);
            acc[rr] = v;
        }
        if ((t & 63) == 0) {
            const int w = t >> 6;
#pragma unroll
            for (int rr = 0; rr < 8; ++rr) ws[w][rr] = acc[rr];
        }
        __syncthreads();
        if (t < 8) A_out[r0 + t] = ws[0][t] + ws[1][t] + ws[2][t] + ws[3][t];
    }
}

// ---------- Kernel B: build l2 from (a,b,l2s); dot w23 (L3-resident) -> l3 ----------
// 512 blocks, 4 w23 rows each.
__global__ __launch_bounds__(256) void kB(const float* __restrict__ w23,
                                          const float* __restrict__ a_in,
                                          const float* __restrict__ b_in,
                                          const float* __restrict__ l2s,
                                          const float* __restrict__ l3s,
                                          float* __restrict__ l2_out,
                                          float* __restrict__ l3_out) {
    __shared__ float lds_l2[N2];  // 16 KB
    __shared__ float ws[4][4];
    const int t = threadIdx.x;
    const int blk = blockIdx.x;

    // build l2 = 0.98*l2s + 0.02*tanh(a + 0.3*b) into LDS
    {
        const f4* __restrict__ a4 = reinterpret_cast<const f4*>(a_in);
        const f4* __restrict__ b4 = reinterpret_cast<const f4*>(b_in);
        const f4* __restrict__ s4 = reinterpret_cast<const f4*>(l2s);
        f4* __restrict__ d4 = reinterpret_cast<f4*>(lds_l2);
#pragma unroll
        for (int k = 0; k < 4; ++k) {
            const int i = t + k * 256;
            f4 av = a4[i];
            f4 bv = b4[i];
            f4 sv = s4[i];
            f4 r;
            r.x = fmaf(0.98f, sv.x, 0.02f * tanhf(fmaf(0.3f, bv.x, av.x)));
            r.y = fmaf(0.98f, sv.y, 0.02f * tanhf(fmaf(0.3f, bv.y, av.y)));
            r.z = fmaf(0.98f, sv.z, 0.02f * tanhf(fmaf(0.3f, bv.z, av.z)));
            r.w = fmaf(0.98f, sv.w, 0.02f * tanhf(fmaf(0.3f, bv.w, av.w)));
            d4[i] = r;
        }
    }
    __syncthreads();
    // publish l2 (blocks 0..15 cover 4096 elems)
    if (blk < 16) {
        const int i = blk * 256 + t;
        l2_out[i] = lds_l2[i];
    }

    // 4 w23 rows @ lds_l2  (w23@lds_l2 == w23@l2 exactly)
    const int r0 = blk * 4;
    const f4* __restrict__ w0 = reinterpret_cast<const f4*>(w23) + (size_t)r0 * (N2 / 4);
    const f4* __restrict__ w1 = w0 + (N2 / 4);
    const f4* __restrict__ w2 = w1 + (N2 / 4);
    const f4* __restrict__ w3 = w2 + (N2 / 4);
    const f4* __restrict__ xl = reinterpret_cast<const f4*>(lds_l2);
    float a0 = 0.f, a1 = 0.f, a2 = 0.f, a3 = 0.f;
#pragma unroll
    for (int k = 0; k < 4; ++k) {
        const int i = t + k * 256;
        f4 xv = xl[i];
        a0 = dot4(w0[i], xv, a0);
        a1 = dot4(w1[i], xv, a1);
        a2 = dot4(w2[i], xv, a2);
        a3 = dot4(w3[i], xv, a3);
    }
#pragma unroll
    for (int off = 32; off; off >>= 1) {
        a0 += __shfl_down(a0, off, 64);
        a1 += __shfl_down(a1, off, 64);
        a2 += __shfl_down(a2, off, 64);
        a3 += __shfl_down(a3, off, 64);
    }
    if ((t & 63) == 0) {
        const int w = t >> 6;
        ws[w][0] = a0; ws[w][1] = a1; ws[w][2] = a2; ws[w][3] = a3;
    }
    __syncthreads();
    if (t < 4) {
        const int r = r0 + t;
        float tot = ws[0][t] + ws[1][t] + ws[2][t] + ws[3][t];
        l3_out[r] = 0.99f * l3s[r] + 0.01f * tanhf(tot);
    }
}

// ---------- Kernel C: all scalar reductions, single block, 2 barriers ----------
__global__ __launch_bounds__(1024) void k_fin(const float* __restrict__ out,
                                              const float* __restrict__ corr_in,
                                              const float* __restrict__ coh_in,
                                              float* __restrict__ scal) {
    __shared__ double sred[16][13];
    __shared__ double fin[13];
    const int t = threadIdx.x;
    const f4* __restrict__ o4 = reinterpret_cast<const f4*>(out);
    // f4 offsets: l1 @ 0 (2048), l2 @ 2048 (1024), l3 @ 3072 (512)

    double p[13];
#pragma unroll
    for (int j = 0; j < 13; ++j) p[j] = 0.0;

    for (int i = t; i < 3584; i += 1024) {
        f4 v = o4[i];
#pragma unroll
        for (int c = 0; c < 4; ++c) {
            double d = (double)v[c];
            p[0] += fabs(d); p[1] += d; p[2] += d * d;
        }
    }
    {
        f4 x = o4[t];
        f4 y = o4[2048 + t];
#pragma unroll
        for (int c = 0; c < 4; ++c) {
            double dx = (double)x[c], dy = (double)y[c];
            p[3] += dx; p[4] += dy; p[5] += dx * dx; p[6] += dy * dy; p[7] += dx * dy;
        }
    }
    if (t < 512) {
        f4 x = o4[2048 + t];
        f4 y = o4[3072 + t];
#pragma unroll
        for (int c = 0; c < 4; ++c) {
            double dx = (double)x[c], dy = (double)y[c];
            p[8] += dx; p[9] += dy; p[10] += dx * dx; p[11] += dy * dy; p[12] += dx * dy;
        }
    }

#pragma unroll
    for (int j = 0; j < 13; ++j) {
        double v = p[j];
#pragma unroll
        for (int off = 32; off; off >>= 1) v += __shfl_down(v, off, 64);
        p[j] = v;
    }
    if ((t & 63) == 0) {
        const int w = t >> 6;
#pragma unroll
        for (int j = 0; j < 13; ++j) sred[w][j] = p[j];
    }
    __syncthreads();
    if (t < 13) {
        double s = 0.0;
#pragma unroll
        for (int w = 0; w < 16; ++w) s += sred[w][t];
        fin[t] = s;
    }
    __syncthreads();

    if (t == 0) {
        const double n12 = (double)N2;
        const double n23 = (double)N3;
        const double nall = (double)(N1 + N2 + N3);

        double sxy12 = fin[7] - fin[3] * fin[4] / n12;
        double sxx12 = fin[5] - fin[3] * fin[3] / n12;
        double syy12 = fin[6] - fin[4] * fin[4] / n12;
        double den12 = sqrt(sxx12 * syy12);
        double c12 = (den12 > 0.0 && isfinite(den12)) ? sxy12 / den12 : 0.0;

        double sxy23 = fin[12] - fin[8] * fin[9] / n23;
        double sxx23 = fin[10] - fin[8] * fin[8] / n23;
        double syy23 = fin[11] - fin[9] * fin[9] / n23;
        double den23 = sqrt(sxx23 * syy23);
        double c23 = (den23 > 0.0 && isfinite(den23)) ? sxy23 / den23 : 0.0;

        double corr_new = 0.9 * (double)corr_in[0] + 0.1 * (c12 + c23) * 0.5;

        double total = fin[0];
        double var = (fin[2] - fin[1] * fin[1] / nall) / (nall - 1.0);
        double coh = total / (var + 1e-6);
        coh = fmin(fmax(coh, 0.0), 10.0);
        double coh_new = 0.9 * (double)coh_in[0] + 0.1 * coh;

        scal[0] = (float)corr_new;
        scal[1] = (float)coh_new;
        scal[2] = (float)(total / nall);
    }
}

extern "C" void kernel_launch(void* const* d_in, const int* in_sizes, int n_in,
                              void* d_out, int out_size, void* d_ws, size_t ws_size,
                              hipStream_t stream) {
    const float* smi     = (const float*)d_in[0];
    const float* l1s     = (const float*)d_in[1];
    const float* l2s     = (const float*)d_in[2];
    const float* l3s     = (const float*)d_in[3];
    const float* w12     = (const float*)d_in[4];
    const float* w23     = (const float*)d_in[5];
    const float* w32     = (const float*)d_in[6];
    // d_in[7] = w21 is UNUSED by the reference — never read (saves 134 MB).
    const float* corr_in = (const float*)d_in[8];
    const float* coh_in  = (const float*)d_in[9];

    float* out = (float*)d_out;
    float* l1 = out;
    float* l2 = out + N1;
    float* l3 = out + N1 + N2;
    float* scal = out + N1 + N2 + N3;

    float* a_ws = (float*)d_ws;          // 4096
    float* b_ws = a_ws + N2;             // 4096
    float* A_ws = b_ws + N2;             // 2048 (L3-prefetch byproduct, unused)

    kA<<<dim3(1536), dim3(256), 0, stream>>>(smi, l1s, w12, w32, w23, l3s, l2s,
                                             a_ws, b_ws, A_ws, l1);
    kB<<<dim3(512), dim3(256), 0, stream>>>(w23, a_ws, b_ws, l2s, l3s, l2, l3);
    k_fin<<<dim3(1), dim3(1024), 0, stream>>>(out, corr_in, coh_in, scal);
}

// Round 8
// 49.776 us; speedup vs baseline: 1.2144x; 1.2144x over previous
//
#include <hip/hip_runtime.h>
#include <math.h>

#define N1 8192
#define N2 4096
#define N3 2048

typedef float f4 __attribute__((ext_vector_type(4)));

__device__ __forceinline__ float dot4(f4 u, f4 x, float acc) {
    return fmaf(u.x, x.x, fmaf(u.y, x.y, fmaf(u.z, x.z, fmaf(u.w, x.w, acc))));
}

// ---------- Kernel 0 (k_pre): w32@l3_state (4 rows/block, 1024 blocks, exactly 4/CU) ----------
// Blocks 0..31 ALSO compute their 256 elements of l1 = 0.95*l1s + 0.05*tanh(smi)
// (2 KB of reads + 256 tanh — hidden under the block's 64 KB w32 stream; no extra blocks,
//  so the grid stays exactly 4 blocks/CU with no straggler tail).
__global__ __launch_bounds__(256) void k_pre(const float* __restrict__ smi,
                                             const float* __restrict__ l1s,
                                             float* __restrict__ l1,
                                             const float* __restrict__ w32,
                                             const float* __restrict__ l3s,
                                             float* __restrict__ t2) {
    __shared__ float ws[4][4];
    const int b = blockIdx.x;
    const int t = threadIdx.x;
    const int r0 = b * 4;
    const f4* __restrict__ w0 = reinterpret_cast<const f4*>(w32) + (size_t)r0 * (N3 / 4);
    const f4* __restrict__ w1 = w0 + (N3 / 4);
    const f4* __restrict__ w2 = w1 + (N3 / 4);
    const f4* __restrict__ w3 = w2 + (N3 / 4);
    const f4* __restrict__ x = reinterpret_cast<const f4*>(l3s);

    float a0 = 0.f, a1 = 0.f, a2 = 0.f, a3 = 0.f;
#pragma unroll
    for (int k = 0; k < (N3 / 4) / 256; ++k) {  // 2 iters
        const int i = t + k * 256;
        f4 xv = x[i];
        a0 = dot4(__builtin_nontemporal_load(&w0[i]), xv, a0);
        a1 = dot4(__builtin_nontemporal_load(&w1[i]), xv, a1);
        a2 = dot4(__builtin_nontemporal_load(&w2[i]), xv, a2);
        a3 = dot4(__builtin_nontemporal_load(&w3[i]), xv, a3);
    }

    // fused l1 update on the first 32 blocks (overlaps the w32 loads above)
    if (b < 32) {
        const int i = b * 256 + t;
        l1[i] = 0.95f * l1s[i] + 0.05f * tanhf(smi[i]);
    }

#pragma unroll
    for (int off = 32; off; off >>= 1) {
        a0 += __shfl_down(a0, off, 64);
        a1 += __shfl_down(a1, off, 64);
        a2 += __shfl_down(a2, off, 64);
        a3 += __shfl_down(a3, off, 64);
    }
    if ((t & 63) == 0) {
        const int w = t >> 6;
        ws[w][0] = a0; ws[w][1] = a1; ws[w][2] = a2; ws[w][3] = a3;
    }
    __syncthreads();
    if (t < 4) {
        t2[r0 + t] = ws[0][t] + ws[1][t] + ws[2][t] + ws[3][t];
    }
}

// ---------- Kernel 2: FOUR rows of w12 per block (1024 blocks, 4/CU) ----------
// l2[r] = 0.98*l2_state[r] + 0.02*tanh( w12[r,:]@l1 + 0.3*t2[r] )
__global__ __launch_bounds__(256) void k_l2(const float* __restrict__ w12,
                                            const float* __restrict__ l1,
                                            const float* __restrict__ t2,
                                            const float* __restrict__ l2s,
                                            float* __restrict__ l2) {
    __shared__ float ws[4][4];
    const int r0 = blockIdx.x * 4;
    const int t = threadIdx.x;
    const f4* __restrict__ w0 = reinterpret_cast<const f4*>(w12) + (size_t)r0 * (N1 / 4);
    const f4* __restrict__ w1 = w0 + (N1 / 4);
    const f4* __restrict__ w2 = w1 + (N1 / 4);
    const f4* __restrict__ w3 = w2 + (N1 / 4);
    const f4* __restrict__ x = reinterpret_cast<const f4*>(l1);

    float a0 = 0.f, a1 = 0.f, a2 = 0.f, a3 = 0.f;
#pragma unroll
    for (int k = 0; k < (N1 / 4) / 256; ++k) {  // 8 iters
        const int i = t + k * 256;
        f4 xv = x[i];
        a0 = dot4(__builtin_nontemporal_load(&w0[i]), xv, a0);
        a1 = dot4(__builtin_nontemporal_load(&w1[i]), xv, a1);
        a2 = dot4(__builtin_nontemporal_load(&w2[i]), xv, a2);
        a3 = dot4(__builtin_nontemporal_load(&w3[i]), xv, a3);
    }
#pragma unroll
    for (int off = 32; off; off >>= 1) {
        a0 += __shfl_down(a0, off, 64);
        a1 += __shfl_down(a1, off, 64);
        a2 += __shfl_down(a2, off, 64);
        a3 += __shfl_down(a3, off, 64);
    }
    if ((t & 63) == 0) {
        const int w = t >> 6;
        ws[w][0] = a0; ws[w][1] = a1; ws[w][2] = a2; ws[w][3] = a3;
    }
    __syncthreads();
    if (t < 4) {
        const int r = r0 + t;
        float tot = ws[0][t] + ws[1][t] + ws[2][t] + ws[3][t] + 0.3f * t2[r];
        l2[r] = 0.98f * l2s[r] + 0.02f * tanhf(tot);
    }
}

// ---------- Kernel 3: FOUR rows of w23 per block (512 blocks, 2/CU) ----------
// l3[r] = 0.99*l3_state[r] + 0.01*tanh( w23[r,:]@l2 )
__global__ __launch_bounds__(256) void k_l3(const float* __restrict__ w23,
                                            const float* __restrict__ l2,
                                            const float* __restrict__ l3s,
                                            float* __restrict__ l3) {
    __shared__ float ws[4][4];
    const int r0 = blockIdx.x * 4;
    const int t = threadIdx.x;
    const f4* __restrict__ w0 = reinterpret_cast<const f4*>(w23) + (size_t)r0 * (N2 / 4);
    const f4* __restrict__ w1 = w0 + (N2 / 4);
    const f4* __restrict__ w2 = w1 + (N2 / 4);
    const f4* __restrict__ w3 = w2 + (N2 / 4);
    const f4* __restrict__ x = reinterpret_cast<const f4*>(l2);

    float a0 = 0.f, a1 = 0.f, a2 = 0.f, a3 = 0.f;
#pragma unroll
    for (int k = 0; k < (N2 / 4) / 256; ++k) {  // 4 iters
        const int i = t + k * 256;
        f4 xv = x[i];
        a0 = dot4(__builtin_nontemporal_load(&w0[i]), xv, a0);
        a1 = dot4(__builtin_nontemporal_load(&w1[i]), xv, a1);
        a2 = dot4(__builtin_nontemporal_load(&w2[i]), xv, a2);
        a3 = dot4(__builtin_nontemporal_load(&w3[i]), xv, a3);
    }
#pragma unroll
    for (int off = 32; off; off >>= 1) {
        a0 += __shfl_down(a0, off, 64);
        a1 += __shfl_down(a1, off, 64);
        a2 += __shfl_down(a2, off, 64);
        a3 += __shfl_down(a3, off, 64);
    }
    if ((t & 63) == 0) {
        const int w = t >> 6;
        ws[w][0] = a0; ws[w][1] = a1; ws[w][2] = a2; ws[w][3] = a3;
    }
    __syncthreads();
    if (t < 4) {
        const int r = r0 + t;
        float tot = ws[0][t] + ws[1][t] + ws[2][t] + ws[3][t];
        l3[r] = 0.99f * l3s[r] + 0.01f * tanhf(tot);
    }
}

// ---------- Kernel 4: all scalar reductions, single block, 2 barriers ----------
// moments: [0]=sum|v| [1]=sum v [2]=sum v^2 over concat(l1,l2,l3)
//          [3..7]  = sx,sy,sxx,syy,sxy over (l1[:4096], l2)
//          [8..12] = sx,sy,sxx,syy,sxy over (l2[:2048], l3)
__global__ __launch_bounds__(1024) void k_fin(const float* __restrict__ out,
                                              const float* __restrict__ corr_in,
                                              const float* __restrict__ coh_in,
                                              float* __restrict__ scal) {
    __shared__ double sred[16][13];
    __shared__ double fin[13];
    const int t = threadIdx.x;
    const f4* __restrict__ o4 = reinterpret_cast<const f4*>(out);
    // f4 offsets: l1 @ 0 (2048), l2 @ 2048 (1024), l3 @ 3072 (512)

    double p[13];
#pragma unroll
    for (int j = 0; j < 13; ++j) p[j] = 0.0;

    for (int i = t; i < 3584; i += 1024) {  // all 14336 elems
        f4 v = o4[i];
#pragma unroll
        for (int c = 0; c < 4; ++c) {
            double d = (double)v[c];
            p[0] += fabs(d); p[1] += d; p[2] += d * d;
        }
    }
    {  // (l1[:4096], l2)
        f4 x = o4[t];
        f4 y = o4[2048 + t];
#pragma unroll
        for (int c = 0; c < 4; ++c) {
            double dx = (double)x[c], dy = (double)y[c];
            p[3] += dx; p[4] += dy; p[5] += dx * dx; p[6] += dy * dy; p[7] += dx * dy;
        }
    }
    if (t < 512) {  // (l2[:2048], l3)
        f4 x = o4[2048 + t];
        f4 y = o4[3072 + t];
#pragma unroll
        for (int c = 0; c < 4; ++c) {
            double dx = (double)x[c], dy = (double)y[c];
            p[8] += dx; p[9] += dy; p[10] += dx * dx; p[11] += dy * dy; p[12] += dx * dy;
        }
    }

#pragma unroll
    for (int j = 0; j < 13; ++j) {
        double v = p[j];
#pragma unroll
        for (int off = 32; off; off >>= 1) v += __shfl_down(v, off, 64);
        p[j] = v;
    }
    if ((t & 63) == 0) {
        const int w = t >> 6;
#pragma unroll
        for (int j = 0; j < 13; ++j) sred[w][j] = p[j];
    }
    __syncthreads();
    if (t < 13) {
        double s = 0.0;
#pragma unroll
        for (int w = 0; w < 16; ++w) s += sred[w][t];
        fin[t] = s;
    }
    __syncthreads();

    if (t == 0) {
        const double n12 = (double)N2;
        const double n23 = (double)N3;
        const double nall = (double)(N1 + N2 + N3);

        double sxy12 = fin[7] - fin[3] * fin[4] / n12;
        double sxx12 = fin[5] - fin[3] * fin[3] / n12;
        double syy12 = fin[6] - fin[4] * fin[4] / n12;
        double den12 = sqrt(sxx12 * syy12);
        double c12 = (den12 > 0.0 && isfinite(den12)) ? sxy12 / den12 : 0.0;

        double sxy23 = fin[12] - fin[8] * fin[9] / n23;
        double sxx23 = fin[10] - fin[8] * fin[8] / n23;
        double syy23 = fin[11] - fin[9] * fin[9] / n23;
        double den23 = sqrt(sxx23 * syy23);
        double c23 = (den23 > 0.0 && isfinite(den23)) ? sxy23 / den23 : 0.0;

        double corr_new = 0.9 * (double)corr_in[0] + 0.1 * (c12 + c23) * 0.5;

        double total = fin[0];
        double var = (fin[2] - fin[1] * fin[1] / nall) / (nall - 1.0);
        double coh = total / (var + 1e-6);
        coh = fmin(fmax(coh, 0.0), 10.0);
        double coh_new = 0.9 * (double)coh_in[0] + 0.1 * coh;

        scal[0] = (float)corr_new;
        scal[1] = (float)coh_new;
        scal[2] = (float)(total / nall);
    }
}

extern "C" void kernel_launch(void* const* d_in, const int* in_sizes, int n_in,
                              void* d_out, int out_size, void* d_ws, size_t ws_size,
                              hipStream_t stream) {
    const float* smi     = (const float*)d_in[0];
    const float* l1s     = (const float*)d_in[1];
    const float* l2s     = (const float*)d_in[2];
    const float* l3s     = (const float*)d_in[3];
    const float* w12     = (const float*)d_in[4];
    const float* w23     = (const float*)d_in[5];
    const float* w32     = (const float*)d_in[6];
    // d_in[7] = w21 is UNUSED by the reference — never read (saves 134 MB).
    const float* corr_in = (const float*)d_in[8];
    const float* coh_in  = (const float*)d_in[9];

    float* out = (float*)d_out;
    float* l1 = out;
    float* l2 = out + N1;
    float* l3 = out + N1 + N2;
    float* scal = out + N1 + N2 + N3;
    float* t2 = (float*)d_ws;  // 4096 floats of scratch

    k_pre<<<dim3(N2 / 4), dim3(256), 0, stream>>>(smi, l1s, l1, w32, l3s, t2);
    k_l2<<<dim3(N2 / 4), dim3(256), 0, stream>>>(w12, l1, t2, l2s, l2);
    k_l3<<<dim3(N3 / 4), dim3(256), 0, stream>>>(w23, l2, l3s, l3);
    k_fin<<<dim3(1), dim3(1024), 0, stream>>>(out, corr_in, coh_in, scal);
}

// Round 9
// 48.252 us; speedup vs baseline: 1.2528x; 1.0316x over previous
//
#include <hip/hip_runtime.h>
#include <math.h>

#define N1 8192
#define N2 4096
#define N3 2048

typedef float f4 __attribute__((ext_vector_type(4)));

// ---------- Kernel 0 (k_pre): fused l1-update + w32@l3_state precompute ----------
// blocks [0,32):    l1 = 0.95*l1_state + 0.05*tanh(smi)      (8192 elems)
// blocks [32,1056): t2[r] = w32[r,:] @ l3_state, 4 rows/block (4096 rows)
__global__ __launch_bounds__(256) void k_pre(const float* __restrict__ smi,
                                             const float* __restrict__ l1s,
                                             float* __restrict__ l1,
                                             const float* __restrict__ w32,
                                             const float* __restrict__ l3s,
                                             float* __restrict__ t2) {
    const int b = blockIdx.x;
    const int t = threadIdx.x;
    if (b < 32) {
        const int i = b * 256 + t;
        l1[i] = 0.95f * l1s[i] + 0.05f * tanhf(smi[i]);
        return;
    }
    __shared__ float ws[4][4];
    const int r0 = (b - 32) * 4;
    const f4* __restrict__ w0 = reinterpret_cast<const f4*>(w32) + (size_t)r0 * (N3 / 4);
    const f4* __restrict__ w1 = w0 + (N3 / 4);
    const f4* __restrict__ w2 = w1 + (N3 / 4);
    const f4* __restrict__ w3 = w2 + (N3 / 4);
    const f4* __restrict__ x = reinterpret_cast<const f4*>(l3s);

    float a0 = 0.f, a1 = 0.f, a2 = 0.f, a3 = 0.f;
#pragma unroll
    for (int k = 0; k < (N3 / 4) / 256; ++k) {  // 2 iters
        const int i = t + k * 256;
        f4 xv = x[i];
        f4 u0 = __builtin_nontemporal_load(&w0[i]);
        f4 u1 = __builtin_nontemporal_load(&w1[i]);
        f4 u2 = __builtin_nontemporal_load(&w2[i]);
        f4 u3 = __builtin_nontemporal_load(&w3[i]);
        a0 = fmaf(u0.x, xv.x, fmaf(u0.y, xv.y, fmaf(u0.z, xv.z, fmaf(u0.w, xv.w, a0))));
        a1 = fmaf(u1.x, xv.x, fmaf(u1.y, xv.y, fmaf(u1.z, xv.z, fmaf(u1.w, xv.w, a1))));
        a2 = fmaf(u2.x, xv.x, fmaf(u2.y, xv.y, fmaf(u2.z, xv.z, fmaf(u2.w, xv.w, a2))));
        a3 = fmaf(u3.x, xv.x, fmaf(u3.y, xv.y, fmaf(u3.z, xv.z, fmaf(u3.w, xv.w, a3))));
    }
#pragma unroll
    for (int off = 32; off; off >>= 1) {
        a0 += __shfl_down(a0, off, 64);
        a1 += __shfl_down(a1, off, 64);
        a2 += __shfl_down(a2, off, 64);
        a3 += __shfl_down(a3, off, 64);
    }
    if ((t & 63) == 0) {
        const int w = t >> 6;
        ws[w][0] = a0; ws[w][1] = a1; ws[w][2] = a2; ws[w][3] = a3;
    }
    __syncthreads();
    if (t < 4) {
        t2[r0 + t] = ws[0][t] + ws[1][t] + ws[2][t] + ws[3][t];
    }
}

// ---------- Kernel 2: FOUR rows of w12 per block ----------
// l2[r] = 0.98*l2_state[r] + 0.02*tanh( w12[r,:]@l1 + 0.3*t2[r] )
__global__ __launch_bounds__(256) void k_l2(const float* __restrict__ w12,
                                            const float* __restrict__ l1,
                                            const float* __restrict__ t2,
                                            const float* __restrict__ l2s,
                                            float* __restrict__ l2) {
    __shared__ float ws[4][4];
    const int r0 = blockIdx.x * 4;
    const int t = threadIdx.x;
    const f4* __restrict__ w0 = reinterpret_cast<const f4*>(w12) + (size_t)r0 * (N1 / 4);
    const f4* __restrict__ w1 = w0 + (N1 / 4);
    const f4* __restrict__ w2 = w1 + (N1 / 4);
    const f4* __restrict__ w3 = w2 + (N1 / 4);
    const f4* __restrict__ x = reinterpret_cast<const f4*>(l1);

    float a0 = 0.f, a1 = 0.f, a2 = 0.f, a3 = 0.f;
#pragma unroll
    for (int k = 0; k < (N1 / 4) / 256; ++k) {  // 8 iters
        const int i = t + k * 256;
        f4 xv = x[i];
        f4 u0 = __builtin_nontemporal_load(&w0[i]);
        f4 u1 = __builtin_nontemporal_load(&w1[i]);
        f4 u2 = __builtin_nontemporal_load(&w2[i]);
        f4 u3 = __builtin_nontemporal_load(&w3[i]);
        a0 = fmaf(u0.x, xv.x, fmaf(u0.y, xv.y, fmaf(u0.z, xv.z, fmaf(u0.w, xv.w, a0))));
        a1 = fmaf(u1.x, xv.x, fmaf(u1.y, xv.y, fmaf(u1.z, xv.z, fmaf(u1.w, xv.w, a1))));
        a2 = fmaf(u2.x, xv.x, fmaf(u2.y, xv.y, fmaf(u2.z, xv.z, fmaf(u2.w, xv.w, a2))));
        a3 = fmaf(u3.x, xv.x, fmaf(u3.y, xv.y, fmaf(u3.z, xv.z, fmaf(u3.w, xv.w, a3))));
    }
#pragma unroll
    for (int off = 32; off; off >>= 1) {
        a0 += __shfl_down(a0, off, 64);
        a1 += __shfl_down(a1, off, 64);
        a2 += __shfl_down(a2, off, 64);
        a3 += __shfl_down(a3, off, 64);
    }
    if ((t & 63) == 0) {
        const int w = t >> 6;
        ws[w][0] = a0; ws[w][1] = a1; ws[w][2] = a2; ws[w][3] = a3;
    }
    __syncthreads();
    if (t < 4) {
        const int r = r0 + t;
        float tot = ws[0][t] + ws[1][t] + ws[2][t] + ws[3][t] + 0.3f * t2[r];
        l2[r] = 0.98f * l2s[r] + 0.02f * tanhf(tot);
    }
}

// ---------- Kernel 3: FOUR rows of w23 per block ----------
// l3[r] = 0.99*l3_state[r] + 0.01*tanh( w23[r,:]@l2 )
__global__ __launch_bounds__(256) void k_l3(const float* __restrict__ w23,
                                            const float* __restrict__ l2,
                                            const float* __restrict__ l3s,
                                            float* __restrict__ l3) {
    __shared__ float ws[4][4];
    const int r0 = blockIdx.x * 4;
    const int t = threadIdx.x;
    const f4* __restrict__ w0 = reinterpret_cast<const f4*>(w23) + (size_t)r0 * (N2 / 4);
    const f4* __restrict__ w1 = w0 + (N2 / 4);
    const f4* __restrict__ w2 = w1 + (N2 / 4);
    const f4* __restrict__ w3 = w2 + (N2 / 4);
    const f4* __restrict__ x = reinterpret_cast<const f4*>(l2);

    float a0 = 0.f, a1 = 0.f, a2 = 0.f, a3 = 0.f;
#pragma unroll
    for (int k = 0; k < (N2 / 4) / 256; ++k) {  // 4 iters
        const int i = t + k * 256;
        f4 xv = x[i];
        f4 u0 = __builtin_nontemporal_load(&w0[i]);
        f4 u1 = __builtin_nontemporal_load(&w1[i]);
        f4 u2 = __builtin_nontemporal_load(&w2[i]);
        f4 u3 = __builtin_nontemporal_load(&w3[i]);
        a0 = fmaf(u0.x, xv.x, fmaf(u0.y, xv.y, fmaf(u0.z, xv.z, fmaf(u0.w, xv.w, a0))));
        a1 = fmaf(u1.x, xv.x, fmaf(u1.y, xv.y, fmaf(u1.z, xv.z, fmaf(u1.w, xv.w, a1))));
        a2 = fmaf(u2.x, xv.x, fmaf(u2.y, xv.y, fmaf(u2.z, xv.z, fmaf(u2.w, xv.w, a2))));
        a3 = fmaf(u3.x, xv.x, fmaf(u3.y, xv.y, fmaf(u3.z, xv.z, fmaf(u3.w, xv.w, a3))));
    }
#pragma unroll
    for (int off = 32; off; off >>= 1) {
        a0 += __shfl_down(a0, off, 64);
        a1 += __shfl_down(a1, off, 64);
        a2 += __shfl_down(a2, off, 64);
        a3 += __shfl_down(a3, off, 64);
    }
    if ((t & 63) == 0) {
        const int w = t >> 6;
        ws[w][0] = a0; ws[w][1] = a1; ws[w][2] = a2; ws[w][3] = a3;
    }
    __syncthreads();
    if (t < 4) {
        const int r = r0 + t;
        float tot = ws[0][t] + ws[1][t] + ws[2][t] + ws[3][t];
        l3[r] = 0.99f * l3s[r] + 0.01f * tanhf(tot);
    }
}

// ---------- Kernel 4: all scalar reductions, single block, 2 barriers ----------
// moments: [0]=sum|v| [1]=sum v [2]=sum v^2 over concat(l1,l2,l3)
//          [3..7]  = sx,sy,sxx,syy,sxy over (l1[:4096], l2)
//          [8..12] = sx,sy,sxx,syy,sxy over (l2[:2048], l3)
__global__ __launch_bounds__(1024) void k_fin(const float* __restrict__ out,
                                              const float* __restrict__ corr_in,
                                              const float* __restrict__ coh_in,
                                              float* __restrict__ scal) {
    __shared__ double sred[16][13];
    __shared__ double fin[13];
    const int t = threadIdx.x;
    const f4* __restrict__ o4 = reinterpret_cast<const f4*>(out);
    // f4 offsets: l1 @ 0 (2048), l2 @ 2048 (1024), l3 @ 3072 (512)

    double p[13];
#pragma unroll
    for (int j = 0; j < 13; ++j) p[j] = 0.0;

    for (int i = t; i < 3584; i += 1024) {  // all 14336 elems
        f4 v = o4[i];
#pragma unroll
        for (int c = 0; c < 4; ++c) {
            double d = (double)v[c];
            p[0] += fabs(d); p[1] += d; p[2] += d * d;
        }
    }
    {  // (l1[:4096], l2)
        f4 x = o4[t];
        f4 y = o4[2048 + t];
#pragma unroll
        for (int c = 0; c < 4; ++c) {
            double dx = (double)x[c], dy = (double)y[c];
            p[3] += dx; p[4] += dy; p[5] += dx * dx; p[6] += dy * dy; p[7] += dx * dy;
        }
    }
    if (t < 512) {  // (l2[:2048], l3)
        f4 x = o4[2048 + t];
        f4 y = o4[3072 + t];
#pragma unroll
        for (int c = 0; c < 4; ++c) {
            double dx = (double)x[c], dy = (double)y[c];
            p[8] += dx; p[9] += dy; p[10] += dx * dx; p[11] += dy * dy; p[12] += dx * dy;
        }
    }

#pragma unroll
    for (int j = 0; j < 13; ++j) {
        double v = p[j];
#pragma unroll
        for (int off = 32; off; off >>= 1) v += __shfl_down(v, off, 64);
        p[j] = v;
    }
    if ((t & 63) == 0) {
        const int w = t >> 6;
#pragma unroll
        for (int j = 0; j < 13; ++j) sred[w][j] = p[j];
    }
    __syncthreads();
    if (t < 13) {
        double s = 0.0;
#pragma unroll
        for (int w = 0; w < 16; ++w) s += sred[w][t];
        fin[t] = s;
    }
    __syncthreads();

    if (t == 0) {
        const double n12 = (double)N2;
        const double n23 = (double)N3;
        const double nall = (double)(N1 + N2 + N3);

        double sxy12 = fin[7] - fin[3] * fin[4] / n12;
        double sxx12 = fin[5] - fin[3] * fin[3] / n12;
        double syy12 = fin[6] - fin[4] * fin[4] / n12;
        double den12 = sqrt(sxx12 * syy12);
        double c12 = (den12 > 0.0 && isfinite(den12)) ? sxy12 / den12 : 0.0;

        double sxy23 = fin[12] - fin[8] * fin[9] / n23;
        double sxx23 = fin[10] - fin[8] * fin[8] / n23;
        double syy23 = fin[11] - fin[9] * fin[9] / n23;
        double den23 = sqrt(sxx23 * syy23);
        double c23 = (den23 > 0.0 && isfinite(den23)) ? sxy23 / den23 : 0.0;

        double corr_new = 0.9 * (double)corr_in[0] + 0.1 * (c12 + c23) * 0.5;

        double total = fin[0];
        double var = (fin[2] - fin[1] * fin[1] / nall) / (nall - 1.0);
        double coh = total / (var + 1e-6);
        coh = fmin(fmax(coh, 0.0), 10.0);
        double coh_new = 0.9 * (double)coh_in[0] + 0.1 * coh;

        scal[0] = (float)corr_new;
        scal[1] = (float)coh_new;
        scal[2] = (float)(total / nall);
    }
}

extern "C" void kernel_launch(void* const* d_in, const int* in_sizes, int n_in,
                              void* d_out, int out_size, void* d_ws, size_t ws_size,
                              hipStream_t stream) {
    const float* smi     = (const float*)d_in[0];
    const float* l1s     = (const float*)d_in[1];
    const float* l2s     = (const float*)d_in[2];
    const float* l3s     = (const float*)d_in[3];
    const float* w12     = (const float*)d_in[4];
    const float* w23     = (const float*)d_in[5];
    const float* w32     = (const float*)d_in[6];
    // d_in[7] = w21 is UNUSED by the reference — never read (saves 134 MB).
    const float* corr_in = (const float*)d_in[8];
    const float* coh_in  = (const float*)d_in[9];

    float* out = (float*)d_out;
    float* l1 = out;
    float* l2 = out + N1;
    float* l3 = out + N1 + N2;
    float* scal = out + N1 + N2 + N3;
    float* t2 = (float*)d_ws;  // 4096 floats of scratch

    k_pre<<<dim3(32 + N2 / 4), dim3(256), 0, stream>>>(smi, l1s, l1, w32, l3s, t2);
    k_l2<<<dim3(N2 / 4), dim3(256), 0, stream>>>(w12, l1, t2, l2s, l2);
    k_l3<<<dim3(N3 / 4), dim3(256), 0, stream>>>(w23, l2, l3s, l3);
    k_fin<<<dim3(1), dim3(1024), 0, stream>>>(out, corr_in, coh_in, scal);
}